// Round 26
// baseline (899.605 us; speedup 1.0000x reference)
//
#include <hip/hip_runtime.h>

// VectorQuantizer: B=32768, K=8192, D=256, fp32.
// out layout (flat float): z_q [B*D], vq_loss [1], commit [1], indices-as-float [B]
// ws layout: ebf bf16[K*D] (4MB) | sz float[B] | partial float[B/4]
//
// Strategy (r19-r26): MFMA candidate filter + exact fp32 verify.
//  scan r26: fat stages + fat blocks. r25 (LDS-shared staging, 16KB stages)
//    still paid the measured ~1400cyc/barrier-iteration convoy 512x/CU.
//    Now: 4 tiles (64 codes)/stage double-buffered (2x32KB LDS -> 1 blk/CU),
//    128 rows/block (4 waves x 32 rows: TWO A-fragment sets/wave, so each
//    staged B fragment feeds 2 MFMAs). Grid 256 = 1 block/CU. Barrier
//    iterations/CU: 512 -> 128; compute/stage ~800cyc hides staging.
//  emission: per-lane running max (16-lane sync every 2 stages = 8 tiles),
//    emit codes with dot >= runmax - M into the row's 255-slot buffer (zq).
//    M = 4e-5 + 3.2e-5*||z|| = 2x rigorous bf16 error bound.
//  exact: fp32 FMA chain (ascending d, bit-identical verified numerics) over
//    candidates; first-index ties; fused gather/zq/loss; full-scan fallback.
// MFMA fragments (16x16x32 bf16, validated r20): A row=lane&15,
// k=(lane>>4)*8+i; B col=lane&15 same k; C/D col=lane&15, row=(lane>>4)*4+reg.

namespace {
constexpr int NB = 32768;
constexpr int NK = 8192;
constexpr int ND = 256;
constexpr int NSTAGE = NK / 64;  // 128 stages of 4 tiles (64 codes)

typedef __attribute__((ext_vector_type(8))) short sh8;
typedef __attribute__((ext_vector_type(4))) float f32x4;

__device__ __forceinline__ unsigned short bf16_rne(float f) {
  unsigned int u = __float_as_uint(f);
  u += 0x7FFFu + ((u >> 16) & 1u);
  return (unsigned short)(u >> 16);
}

// ---- S[row] = ||z_row||^2 ; also zero the row's candidate counter ----
__global__ void sz_kernel(const float* __restrict__ z, float* __restrict__ sz,
                          float* __restrict__ zq) {
  const int row = blockIdx.x * 4 + (threadIdx.x >> 6);
  const int lane = threadIdx.x & 63;
  const float4 v = reinterpret_cast<const float4*>(z)[(size_t)row * 64 + lane];
  float s = v.x * v.x + v.y * v.y + v.z * v.z + v.w * v.w;
#pragma unroll
  for (int off = 32; off; off >>= 1) s += __shfl_down(s, off, 64);
  if (lane == 0) {
    sz[row] = s;
    ((int*)(zq + (size_t)row * ND))[0] = 0;  // candidate counter
  }
}

// ---- emb -> bf16 (RNE) ----
__global__ void ebf_kernel(const float* __restrict__ emb,
                           unsigned short* __restrict__ ebf) {
  const int i = blockIdx.x * 256 + threadIdx.x;  // 8 elems per thread
  const float4 a = reinterpret_cast<const float4*>(emb)[i * 2];
  const float4 b = reinterpret_cast<const float4*>(emb)[i * 2 + 1];
  uint4 o;
  o.x = (unsigned)bf16_rne(a.x) | ((unsigned)bf16_rne(a.y) << 16);
  o.y = (unsigned)bf16_rne(a.z) | ((unsigned)bf16_rne(a.w) << 16);
  o.z = (unsigned)bf16_rne(b.x) | ((unsigned)bf16_rne(b.y) << 16);
  o.w = (unsigned)bf16_rne(b.z) | ((unsigned)bf16_rne(b.w) << 16);
  reinterpret_cast<uint4*>(ebf)[i] = o;
}

// ---- MFMA scan: 64KB LDS staging, 128 rows/block, candidate emission ----
__global__ __launch_bounds__(256, 1) void mfma_scan(
    const float* __restrict__ z, const unsigned short* __restrict__ ebf,
    const float* __restrict__ sz, float* __restrict__ zqout) {
  // [buf][tile][q][lane] : fragment-major, 16B per lane slot
  __shared__ __align__(16) char ldsbuf[2 * 4 * 8 * 1024];  // 64 KB

  const int lane = threadIdx.x & 63;
  const int w = threadIdx.x >> 6;
  const int r0 = blockIdx.x * 128 + w * 32;  // this wave's 32 rows
  const int cl = lane & 15;                  // A-row / B-col slot
  const int kg = lane >> 4;                  // k-group (0..3)

  // A fragments, 2 sets: rows r0+set*16+cl, k = q*32 + kg*8 + i
  sh8 afrag[2][8];
#pragma unroll
  for (int set = 0; set < 2; ++set) {
    const float* zp = z + (size_t)(r0 + set * 16 + cl) * ND + kg * 8;
#pragma unroll
    for (int q = 0; q < 8; ++q) {
      const float4 f0 = *reinterpret_cast<const float4*>(zp + q * 32);
      const float4 f1 = *reinterpret_cast<const float4*>(zp + q * 32 + 4);
      sh8 a;
      a[0] = (short)bf16_rne(f0.x); a[1] = (short)bf16_rne(f0.y);
      a[2] = (short)bf16_rne(f0.z); a[3] = (short)bf16_rne(f0.w);
      a[4] = (short)bf16_rne(f1.x); a[5] = (short)bf16_rne(f1.y);
      a[6] = (short)bf16_rne(f1.z); a[7] = (short)bf16_rne(f1.w);
      afrag[set][q] = a;
    }
  }

  // per-lane rows: set s, r -> row r0 + set*16 + kg*4 + r
  float M[2][4];
  int* cpb[2][4];
#pragma unroll
  for (int set = 0; set < 2; ++set)
#pragma unroll
    for (int r = 0; r < 4; ++r) {
      const int row = r0 + set * 16 + kg * 4 + r;
      M[set][r] = 4e-5f + 3.2e-5f * sqrtf(sz[row]);
      cpb[set][r] = (int*)(zqout + (size_t)row * ND);
    }

  // stage 4 tiles (32KB) into ldsbuf[buf]; wave w covers q in {2w, 2w+1}
  const char* ebase = (const char*)ebf;
  auto stage_issue = [&](int buf, int s) {
    const int t16 = s * 4;
#pragma unroll
    for (int tile = 0; tile < 4; ++tile) {
#pragma unroll
      for (int qi = 0; qi < 2; ++qi) {
        const int q = w * 2 + qi;
        const char* g = ebase +
            ((size_t)((t16 + tile) * 16 + cl) * ND + q * 32 + kg * 8) * 2;
        char* l = ldsbuf + ((buf * 4 + tile) * 8 + q) * 1024;
        __builtin_amdgcn_global_load_lds(
            (const __attribute__((address_space(1))) unsigned int*)g,
            (__attribute__((address_space(3))) unsigned int*)l, 16, 0, 0);
      }
    }
  };

  auto dotTile = [&](const sh8* a, const sh8* b) -> f32x4 {
    f32x4 c0 = {0.f, 0.f, 0.f, 0.f}, c1 = c0, c2 = c0, c3 = c0;
    c0 = __builtin_amdgcn_mfma_f32_16x16x32_bf16(a[0], b[0], c0, 0, 0, 0);
    c1 = __builtin_amdgcn_mfma_f32_16x16x32_bf16(a[1], b[1], c1, 0, 0, 0);
    c2 = __builtin_amdgcn_mfma_f32_16x16x32_bf16(a[2], b[2], c2, 0, 0, 0);
    c3 = __builtin_amdgcn_mfma_f32_16x16x32_bf16(a[3], b[3], c3, 0, 0, 0);
    c0 = __builtin_amdgcn_mfma_f32_16x16x32_bf16(a[4], b[4], c0, 0, 0, 0);
    c1 = __builtin_amdgcn_mfma_f32_16x16x32_bf16(a[5], b[5], c1, 0, 0, 0);
    c2 = __builtin_amdgcn_mfma_f32_16x16x32_bf16(a[6], b[6], c2, 0, 0, 0);
    c3 = __builtin_amdgcn_mfma_f32_16x16x32_bf16(a[7], b[7], c3, 0, 0, 0);
    return (c0 + c1) + (c2 + c3);
  };

  float runmax[2][4];
  auto syncmax = [&]() {
#pragma unroll
    for (int set = 0; set < 2; ++set)
#pragma unroll
      for (int r = 0; r < 4; ++r) {
        float v = runmax[set][r];
#pragma unroll
        for (int m = 1; m < 16; m <<= 1) v = fmaxf(v, __shfl_xor(v, m, 64));
        runmax[set][r] = v;
      }
  };

  auto emitproc = [&](const sh8* b, int t16) {
#pragma unroll
    for (int set = 0; set < 2; ++set) {
      const f32x4 dot = dotTile(afrag[set], b);
#pragma unroll
      for (int r = 0; r < 4; ++r) {
        if (dot[r] >= runmax[set][r] - M[set][r]) {
          const int slot = atomicAdd(cpb[set][r], 1);
          if (slot < 255) cpb[set][r][1 + slot] = t16 * 16 + cl;
        }
        runmax[set][r] = fmaxf(runmax[set][r], dot[r]);
      }
    }
  };

  auto loadTile = [&](sh8* b, int buf, int tile) {
    const char* base = ldsbuf + ((buf * 4 + tile) * 8) * 1024 + lane * 16;
#pragma unroll
    for (int q = 0; q < 8; ++q)
      b[q] = *reinterpret_cast<const sh8*>(base + q * 1024);
  };

  stage_issue(0, 0);
  __syncthreads();  // stage 0 resident
  {  // bootstrap runmax from tile 0 (re-processed with emission below)
    sh8 b[8];
    loadTile(b, 0, 0);
#pragma unroll
    for (int set = 0; set < 2; ++set) {
      const f32x4 d0 = dotTile(afrag[set], b);
#pragma unroll
      for (int r = 0; r < 4; ++r) runmax[set][r] = d0[r];
    }
    syncmax();
  }

  for (int s = 0; s < NSTAGE; ++s) {
    const int buf = s & 1;
    if (s + 1 < NSTAGE) stage_issue(buf ^ 1, s + 1);  // async into other buf
    sh8 b[8];
#pragma unroll
    for (int tile = 0; tile < 4; ++tile) {
      loadTile(b, buf, tile);
      emitproc(b, s * 4 + tile);
    }
    if (s & 1) syncmax();  // every 2 stages = 8 tiles: bound runmax lag
    __syncthreads();       // drains next stage's loads; guards buf reuse
  }
}

// ---- exact verify + gather + loss partial (4 rows per block) ----
__global__ __launch_bounds__(256, 1) void exact_kernel(
    const float* __restrict__ z, const float* __restrict__ emb,
    const float* __restrict__ sz, float* __restrict__ zq,
    float* __restrict__ idx_f, float* __restrict__ partial) {
  __shared__ float wps[4];
  const int lane = threadIdx.x & 63;
  const int w = threadIdx.x >> 6;
  const int row = blockIdx.x * 4 + w;
  int* cp = (int*)(zq + (size_t)row * ND);
  const int cnt = cp[0];
  const float S = sz[row];
  const float4* zp = reinterpret_cast<const float4*>(z + (size_t)row * ND);

  float bd = 3.4e38f;
  int bc = 0x7fffffff;
  if (cnt >= 1 && cnt <= 255) {
    for (int c = lane; c < cnt; c += 64) {
      const int k = cp[1 + c];
      const float4* ep = reinterpret_cast<const float4*>(emb + (size_t)k * ND);
      float acc = 0.f;
#pragma unroll 8
      for (int q = 0; q < 64; ++q) {  // exact chain, ascending d
        const float4 zz = zp[q];
        const float4 ee = ep[q];
        acc = fmaf(zz.x, ee.x, acc);
        acc = fmaf(zz.y, ee.y, acc);
        acc = fmaf(zz.z, ee.z, acc);
        acc = fmaf(zz.w, ee.w, acc);
      }
      const float dist = fmaf(-2.f, acc, S);
      if (dist < bd || (dist == bd && k < bc)) { bd = dist; bc = k; }
    }
  } else {
    // fallback: full exact scan (overflow/empty — correctness net, ~never)
    for (int code = lane; code < NK; code += 64) {
      const float4* ep = reinterpret_cast<const float4*>(emb + (size_t)code * ND);
      float acc = 0.f;
#pragma unroll 8
      for (int q = 0; q < 64; ++q) {
        const float4 zz = zp[q];
        const float4 ee = ep[q];
        acc = fmaf(zz.x, ee.x, acc);
        acc = fmaf(zz.y, ee.y, acc);
        acc = fmaf(zz.z, ee.z, acc);
        acc = fmaf(zz.w, ee.w, acc);
      }
      const float dist = fmaf(-2.f, acc, S);
      if (dist < bd || (dist == bd && code < bc)) { bd = dist; bc = code; }
    }
  }
  // min-reduce across 64 lanes; lowest code on exact ties
#pragma unroll
  for (int m = 1; m < 64; m <<= 1) {
    const float od = __shfl_xor(bd, m, 64);
    const int oc = __shfl_xor(bc, m, 64);
    if (od < bd || (od == bd && oc < bc)) { bd = od; bc = oc; }
  }
  // fused gather (candidate reads finished; safe to overwrite zq row)
  const float4 e = reinterpret_cast<const float4*>(emb)[(size_t)bc * 64 + lane];
  const float4 zv = zp[lane];
  reinterpret_cast<float4*>(zq)[(size_t)row * 64 + lane] = e;
  const float dx = e.x - zv.x, dy = e.y - zv.y;
  const float dz = e.z - zv.z, dw = e.w - zv.w;
  float s = dx * dx + dy * dy + dz * dz + dw * dw;
#pragma unroll
  for (int off = 32; off; off >>= 1) s += __shfl_down(s, off, 64);
  if (lane == 0) {
    idx_f[row] = (float)bc;
    wps[w] = s;
  }
  __syncthreads();
  if (threadIdx.x == 0)
    partial[blockIdx.x] = wps[0] + wps[1] + wps[2] + wps[3];
}

// ---- deterministic final loss reduction ----
__global__ void loss_kernel(const float* __restrict__ partial, int n,
                            float* __restrict__ out_loss) {
  double s = 0.0;
  for (int i = threadIdx.x; i < n; i += 256) s += (double)partial[i];
  __shared__ double sm[256];
  sm[threadIdx.x] = s;
  __syncthreads();
  for (int st = 128; st; st >>= 1) {
    if (threadIdx.x < st) sm[threadIdx.x] += sm[threadIdx.x + st];
    __syncthreads();
  }
  if (threadIdx.x == 0) {
    float loss = (float)(0.25 * sm[0] / (double)((size_t)NB * ND));
    out_loss[0] = loss;  // vq_loss
    out_loss[1] = loss;  // commitment loss (same forward value)
  }
}

}  // namespace

extern "C" void kernel_launch(void* const* d_in, const int* in_sizes, int n_in,
                              void* d_out, int out_size, void* d_ws, size_t ws_size,
                              hipStream_t stream) {
  const float* z = (const float*)d_in[0];
  const float* emb = (const float*)d_in[1];
  float* out = (float*)d_out;
  float* zq = out;
  float* loss = out + (size_t)NB * ND;
  float* idx_f = out + (size_t)NB * ND + 2;

  unsigned short* ebf = (unsigned short*)d_ws;                      // 4 MB
  float* sz = (float*)((char*)d_ws + (size_t)NK * ND * 2);          // 128 KB
  float* partial = (float*)((char*)d_ws + (size_t)NK * ND * 2 + (size_t)NB * 4);

  sz_kernel<<<NB / 4, 256, 0, stream>>>(z, sz, zq);
  ebf_kernel<<<NK * ND / 8 / 256, 256, 0, stream>>>(emb, ebf);
  mfma_scan<<<NB / 128, 256, 0, stream>>>(z, ebf, sz, zq);
  exact_kernel<<<NB / 4, 256, 0, stream>>>(z, emb, sz, zq, idx_f, partial);
  loss_kernel<<<1, 256, 0, stream>>>(partial, NB / 4, loss);
}

// Round 27
// 733.383 us; speedup vs baseline: 1.2267x; 1.2267x over previous
//
#include <hip/hip_runtime.h>

// VectorQuantizer: B=32768, K=8192, D=256, fp32.
// out layout (flat float): z_q [B*D], vq_loss [1], commit [1], indices-as-float [B]
// ws layout: ebf bf16[K*D] (4MB) | sz float[B] | partial float[B/4]
//
// Strategy (r19-r27): MFMA candidate filter + exact fp32 verify.
//  scan r27 = r25 geometry (64 rows/block, 2 tiles/stage, 512 blocks = 2/CU)
//    + counted-vmcnt pipeline (T3/T4): 3 staging buffers (48KB LDS), prefetch
//    depth 2, barrier = s_waitcnt vmcnt(4) + sched_barrier(0) + raw s_barrier
//    — stage s+1/s+2 loads stay IN FLIGHT across the barrier (r25's
//    __syncthreads drained vmcnt(0) every stage: ~80% of the 2414cyc/stage
//    wall). r26's 64KB fat stage REVERTED (1 blk/CU, occupancy 11.6%).
//    Ordering: iter-s barrier => all waves did compute(s-1) => safe to issue
//    stage s+2 into buf[(s+2)%3] (last read at s-1); vmcnt(4) => stage-s
//    loads (oldest) landed. Emission atomics only over-wait, never under.
//  emission: per-lane running max (16-lane sync every 8 tiles), emit codes
//    with dot >= runmax - M into the row's 255-slot buffer (in zq).
//    M = 4e-5 + 3.2e-5*||z|| = 2x rigorous bf16 error bound.
//  exact: fp32 FMA chain (ascending d, bit-identical verified numerics) over
//    candidates; first-index ties; fused gather/zq/loss; full-scan fallback.
// MFMA fragments (16x16x32 bf16, validated r20): A row=lane&15,
// k=(lane>>4)*8+i; B col=lane&15 same k; C/D col=lane&15, row=(lane>>4)*4+reg.

namespace {
constexpr int NB = 32768;
constexpr int NK = 8192;
constexpr int ND = 256;
constexpr int NSTAGE = NK / 32;  // 256 stages of 2 tiles (32 codes)

typedef __attribute__((ext_vector_type(8))) short sh8;
typedef __attribute__((ext_vector_type(4))) float f32x4;

__device__ __forceinline__ unsigned short bf16_rne(float f) {
  unsigned int u = __float_as_uint(f);
  u += 0x7FFFu + ((u >> 16) & 1u);
  return (unsigned short)(u >> 16);
}

// ---- S[row] = ||z_row||^2 ; also zero the row's candidate counter ----
__global__ void sz_kernel(const float* __restrict__ z, float* __restrict__ sz,
                          float* __restrict__ zq) {
  const int row = blockIdx.x * 4 + (threadIdx.x >> 6);
  const int lane = threadIdx.x & 63;
  const float4 v = reinterpret_cast<const float4*>(z)[(size_t)row * 64 + lane];
  float s = v.x * v.x + v.y * v.y + v.z * v.z + v.w * v.w;
#pragma unroll
  for (int off = 32; off; off >>= 1) s += __shfl_down(s, off, 64);
  if (lane == 0) {
    sz[row] = s;
    ((int*)(zq + (size_t)row * ND))[0] = 0;  // candidate counter
  }
}

// ---- emb -> bf16 (RNE) ----
__global__ void ebf_kernel(const float* __restrict__ emb,
                           unsigned short* __restrict__ ebf) {
  const int i = blockIdx.x * 256 + threadIdx.x;  // 8 elems per thread
  const float4 a = reinterpret_cast<const float4*>(emb)[i * 2];
  const float4 b = reinterpret_cast<const float4*>(emb)[i * 2 + 1];
  uint4 o;
  o.x = (unsigned)bf16_rne(a.x) | ((unsigned)bf16_rne(a.y) << 16);
  o.y = (unsigned)bf16_rne(a.z) | ((unsigned)bf16_rne(a.w) << 16);
  o.z = (unsigned)bf16_rne(b.x) | ((unsigned)bf16_rne(b.y) << 16);
  o.w = (unsigned)bf16_rne(b.z) | ((unsigned)bf16_rne(b.w) << 16);
  reinterpret_cast<uint4*>(ebf)[i] = o;
}

// ---- MFMA scan: LDS-shared B staging, counted-vmcnt pipeline ----
__global__ __launch_bounds__(256, 1) void mfma_scan(
    const float* __restrict__ z, const unsigned short* __restrict__ ebf,
    const float* __restrict__ sz, float* __restrict__ zqout) {
  // [buf(3)][tile(2)][q(8)][lane] : fragment-major, 16B per lane slot
  __shared__ __align__(16) char ldsbuf[3 * 2 * 8 * 1024];  // 48 KB

  const int lane = threadIdx.x & 63;
  const int w = threadIdx.x >> 6;
  const int r0 = blockIdx.x * 64 + w * 16;  // this wave's 16 rows
  const int cl = lane & 15;                 // A-row / B-col slot
  const int kg = lane >> 4;                 // k-group (0..3)

  // A fragments: rows r0+cl, k = q*32 + kg*8 + i  (bf16 on the fly)
  sh8 afrag[8];
  {
    const float* zp = z + (size_t)(r0 + cl) * ND + kg * 8;
#pragma unroll
    for (int q = 0; q < 8; ++q) {
      const float4 f0 = *reinterpret_cast<const float4*>(zp + q * 32);
      const float4 f1 = *reinterpret_cast<const float4*>(zp + q * 32 + 4);
      sh8 a;
      a[0] = (short)bf16_rne(f0.x); a[1] = (short)bf16_rne(f0.y);
      a[2] = (short)bf16_rne(f0.z); a[3] = (short)bf16_rne(f0.w);
      a[4] = (short)bf16_rne(f1.x); a[5] = (short)bf16_rne(f1.y);
      a[6] = (short)bf16_rne(f1.z); a[7] = (short)bf16_rne(f1.w);
      afrag[q] = a;
    }
  }

  // per-lane rows r = r0 + kg*4 + (0..3): margin + candidate buffers
  float M[4];
  int* cpb[4];
#pragma unroll
  for (int r = 0; r < 4; ++r) {
    const int row = r0 + kg * 4 + r;
    M[r] = 4e-5f + 3.2e-5f * sqrtf(sz[row]);
    cpb[r] = (int*)(zqout + (size_t)row * ND);
  }

  // stage 2 tiles (16KB) into ldsbuf[buf]; wave w covers q in {2w, 2w+1}
  // (4 global_load_lds per wave per stage)
  const char* ebase = (const char*)ebf;
  auto stage_issue = [&](int buf, int s) {
    const int t16 = s * 2;
#pragma unroll
    for (int tile = 0; tile < 2; ++tile) {
#pragma unroll
      for (int qi = 0; qi < 2; ++qi) {
        const int q = w * 2 + qi;
        const char* g = ebase +
            ((size_t)((t16 + tile) * 16 + cl) * ND + q * 32 + kg * 8) * 2;
        char* l = ldsbuf + ((buf * 2 + tile) * 8 + q) * 1024;
        __builtin_amdgcn_global_load_lds(
            (const __attribute__((address_space(1))) unsigned int*)g,
            (__attribute__((address_space(3))) unsigned int*)l, 16, 0, 0);
      }
    }
  };

  auto dotTile = [&](const sh8* b) -> f32x4 {
    f32x4 c0 = {0.f, 0.f, 0.f, 0.f}, c1 = c0, c2 = c0, c3 = c0;
    c0 = __builtin_amdgcn_mfma_f32_16x16x32_bf16(afrag[0], b[0], c0, 0, 0, 0);
    c1 = __builtin_amdgcn_mfma_f32_16x16x32_bf16(afrag[1], b[1], c1, 0, 0, 0);
    c2 = __builtin_amdgcn_mfma_f32_16x16x32_bf16(afrag[2], b[2], c2, 0, 0, 0);
    c3 = __builtin_amdgcn_mfma_f32_16x16x32_bf16(afrag[3], b[3], c3, 0, 0, 0);
    c0 = __builtin_amdgcn_mfma_f32_16x16x32_bf16(afrag[4], b[4], c0, 0, 0, 0);
    c1 = __builtin_amdgcn_mfma_f32_16x16x32_bf16(afrag[5], b[5], c1, 0, 0, 0);
    c2 = __builtin_amdgcn_mfma_f32_16x16x32_bf16(afrag[6], b[6], c2, 0, 0, 0);
    c3 = __builtin_amdgcn_mfma_f32_16x16x32_bf16(afrag[7], b[7], c3, 0, 0, 0);
    return (c0 + c1) + (c2 + c3);
  };

  float runmax[4];
  auto syncmax = [&]() {
#pragma unroll
    for (int r = 0; r < 4; ++r) {
      float v = runmax[r];
#pragma unroll
      for (int m = 1; m < 16; m <<= 1) v = fmaxf(v, __shfl_xor(v, m, 64));
      runmax[r] = v;
    }
  };

  auto emitproc = [&](const sh8* b, int t16) {
    const f32x4 dot = dotTile(b);
#pragma unroll
    for (int r = 0; r < 4; ++r) {
      if (dot[r] >= runmax[r] - M[r]) {
        const int slot = atomicAdd(cpb[r], 1);
        if (slot < 255) cpb[r][1 + slot] = t16 * 16 + cl;
      }
      runmax[r] = fmaxf(runmax[r], dot[r]);
    }
  };

  auto loadTile = [&](sh8* b, int buf, int tile) {
    const char* base = ldsbuf + ((buf * 2 + tile) * 8) * 1024 + lane * 16;
#pragma unroll
    for (int q = 0; q < 8; ++q)
      b[q] = *reinterpret_cast<const sh8*>(base + q * 1024);
  };

  // prologue: stages 0,1 in flight; wait for stage 0 only (4 newest remain)
  stage_issue(0, 0);
  stage_issue(1, 1);
  asm volatile("s_waitcnt vmcnt(4)" ::: "memory");
  __builtin_amdgcn_sched_barrier(0);
  __builtin_amdgcn_s_barrier();
  {  // bootstrap runmax from tile 0 (re-processed with emission below)
    sh8 b[8];
    loadTile(b, 0, 0);
    const f32x4 d0 = dotTile(b);
#pragma unroll
    for (int r = 0; r < 4; ++r) runmax[r] = d0[r];
    syncmax();
  }

  for (int s = 0; s < NSTAGE; ++s) {
    const int buf = s % 3;
    // stage-s loads are this wave's oldest outstanding VMEM ops; emission
    // atomics/stores are newer -> vmcnt(4) can only over-wait, never under.
    asm volatile("s_waitcnt vmcnt(4)" ::: "memory");
    __builtin_amdgcn_sched_barrier(0);
    __builtin_amdgcn_s_barrier();  // all waves: stage s landed, compute s-1 done
    if (s + 2 < NSTAGE) stage_issue((s + 2) % 3, s + 2);
    sh8 b[8];
    loadTile(b, buf, 0);
    emitproc(b, s * 2);
    loadTile(b, buf, 1);
    emitproc(b, s * 2 + 1);
    if ((s & 3) == 3) syncmax();  // every 8 tiles: bound runmax lag
  }
}

// ---- exact verify + gather + loss partial (4 rows per block) ----
__global__ __launch_bounds__(256, 1) void exact_kernel(
    const float* __restrict__ z, const float* __restrict__ emb,
    const float* __restrict__ sz, float* __restrict__ zq,
    float* __restrict__ idx_f, float* __restrict__ partial) {
  __shared__ float wps[4];
  const int lane = threadIdx.x & 63;
  const int w = threadIdx.x >> 6;
  const int row = blockIdx.x * 4 + w;
  int* cp = (int*)(zq + (size_t)row * ND);
  const int cnt = cp[0];
  const float S = sz[row];
  const float4* zp = reinterpret_cast<const float4*>(z + (size_t)row * ND);

  float bd = 3.4e38f;
  int bc = 0x7fffffff;
  if (cnt >= 1 && cnt <= 255) {
    for (int c = lane; c < cnt; c += 64) {
      const int k = cp[1 + c];
      const float4* ep = reinterpret_cast<const float4*>(emb + (size_t)k * ND);
      float acc = 0.f;
#pragma unroll 8
      for (int q = 0; q < 64; ++q) {  // exact chain, ascending d
        const float4 zz = zp[q];
        const float4 ee = ep[q];
        acc = fmaf(zz.x, ee.x, acc);
        acc = fmaf(zz.y, ee.y, acc);
        acc = fmaf(zz.z, ee.z, acc);
        acc = fmaf(zz.w, ee.w, acc);
      }
      const float dist = fmaf(-2.f, acc, S);
      if (dist < bd || (dist == bd && k < bc)) { bd = dist; bc = k; }
    }
  } else {
    // fallback: full exact scan (overflow/empty — correctness net, ~never)
    for (int code = lane; code < NK; code += 64) {
      const float4* ep = reinterpret_cast<const float4*>(emb + (size_t)code * ND);
      float acc = 0.f;
#pragma unroll 8
      for (int q = 0; q < 64; ++q) {
        const float4 zz = zp[q];
        const float4 ee = ep[q];
        acc = fmaf(zz.x, ee.x, acc);
        acc = fmaf(zz.y, ee.y, acc);
        acc = fmaf(zz.z, ee.z, acc);
        acc = fmaf(zz.w, ee.w, acc);
      }
      const float dist = fmaf(-2.f, acc, S);
      if (dist < bd || (dist == bd && code < bc)) { bd = dist; bc = code; }
    }
  }
  // min-reduce across 64 lanes; lowest code on exact ties
#pragma unroll
  for (int m = 1; m < 64; m <<= 1) {
    const float od = __shfl_xor(bd, m, 64);
    const int oc = __shfl_xor(bc, m, 64);
    if (od < bd || (od == bd && oc < bc)) { bd = od; bc = oc; }
  }
  // fused gather (candidate reads finished; safe to overwrite zq row)
  const float4 e = reinterpret_cast<const float4*>(emb)[(size_t)bc * 64 + lane];
  const float4 zv = zp[lane];
  reinterpret_cast<float4*>(zq)[(size_t)row * 64 + lane] = e;
  const float dx = e.x - zv.x, dy = e.y - zv.y;
  const float dz = e.z - zv.z, dw = e.w - zv.w;
  float s = dx * dx + dy * dy + dz * dz + dw * dw;
#pragma unroll
  for (int off = 32; off; off >>= 1) s += __shfl_down(s, off, 64);
  if (lane == 0) {
    idx_f[row] = (float)bc;
    wps[w] = s;
  }
  __syncthreads();
  if (threadIdx.x == 0)
    partial[blockIdx.x] = wps[0] + wps[1] + wps[2] + wps[3];
}

// ---- deterministic final loss reduction ----
__global__ void loss_kernel(const float* __restrict__ partial, int n,
                            float* __restrict__ out_loss) {
  double s = 0.0;
  for (int i = threadIdx.x; i < n; i += 256) s += (double)partial[i];
  __shared__ double sm[256];
  sm[threadIdx.x] = s;
  __syncthreads();
  for (int st = 128; st; st >>= 1) {
    if (threadIdx.x < st) sm[threadIdx.x] += sm[threadIdx.x + st];
    __syncthreads();
  }
  if (threadIdx.x == 0) {
    float loss = (float)(0.25 * sm[0] / (double)((size_t)NB * ND));
    out_loss[0] = loss;  // vq_loss
    out_loss[1] = loss;  // commitment loss (same forward value)
  }
}

}  // namespace

extern "C" void kernel_launch(void* const* d_in, const int* in_sizes, int n_in,
                              void* d_out, int out_size, void* d_ws, size_t ws_size,
                              hipStream_t stream) {
  const float* z = (const float*)d_in[0];
  const float* emb = (const float*)d_in[1];
  float* out = (float*)d_out;
  float* zq = out;
  float* loss = out + (size_t)NB * ND;
  float* idx_f = out + (size_t)NB * ND + 2;

  unsigned short* ebf = (unsigned short*)d_ws;                      // 4 MB
  float* sz = (float*)((char*)d_ws + (size_t)NK * ND * 2);          // 128 KB
  float* partial = (float*)((char*)d_ws + (size_t)NK * ND * 2 + (size_t)NB * 4);

  sz_kernel<<<NB / 4, 256, 0, stream>>>(z, sz, zq);
  ebf_kernel<<<NK * ND / 8 / 256, 256, 0, stream>>>(emb, ebf);
  mfma_scan<<<NB / 64, 256, 0, stream>>>(z, ebf, sz, zq);
  exact_kernel<<<NB / 4, 256, 0, stream>>>(z, emb, sz, zq, idx_f, partial);
  loss_kernel<<<1, 256, 0, stream>>>(partial, NB / 4, loss);
}